// Round 11
// baseline (617.442 us; speedup 1.0000x reference)
//
#include <hip/hip_runtime.h>
#include <hip/hip_bf16.h>
#include <math.h>

typedef __hip_bfloat16 bf16;
typedef unsigned short ushort_t;
typedef __bf16 bf16x8 __attribute__((ext_vector_type(8)));
typedef float f32x4 __attribute__((ext_vector_type(4)));

#define TOKENS 50176        // 16 * 3136
#define CW2 512             // windows per chunk (2 chunks)
#define CROWS2 (CW2 * 49)   // 25088 rows per chunk
#define SCALE_ 0.17677669529663687f  // 32^-0.5

__device__ __forceinline__ float b2f(bf16 v) { return __bfloat162float(v); }
__device__ __forceinline__ bf16  f2b(float v) { return __float2bfloat16(v); }

// fast erf-GELU: Abramowitz-Stegun 7.1.26, |err| <= 1.5e-7 (below bf16 rounding)
__device__ __forceinline__ float gelu_f(float v) {
  float x = v * 0.7071067811865475f;
  float ax = fabsf(x);
  float t = 1.f / (1.f + 0.3275911f * ax);
  float poly = ((((1.061405429f * t - 1.453152027f) * t + 1.421413741f) * t
                 - 0.284496736f) * t + 0.254829592f) * t;
  float erfv = 1.f - poly * __expf(-ax * ax);
  erfv = copysignf(erfv, x);
  return 0.5f * v * (1.f + erfv);
}

// ---------------- weight convert: all 4 weights in ONE dispatch ----------------
// Wt[n][k] = bf16(W[k][n]); ranges: wq[384x1152], wp[384x384], w1[384x1536], w2[1536x384]
__global__ __launch_bounds__(256) void wt_all(const float* __restrict__ qkv_w,
                                              const float* __restrict__ proj_w,
                                              const float* __restrict__ mlp_w1,
                                              const float* __restrict__ mlp_w2,
                                              ushort_t* __restrict__ wq,
                                              ushort_t* __restrict__ wp,
                                              ushort_t* __restrict__ w1,
                                              ushort_t* __restrict__ w2) {
  int idx = blockIdx.x * 256 + threadIdx.x;
  const float* W; ushort_t* O; int K, N, loc;
  if (idx < 442368)        { W = qkv_w;  O = wq; K = 384;  N = 1152; loc = idx; }
  else if (idx < 589824)   { W = proj_w; O = wp; K = 384;  N = 384;  loc = idx - 442368; }
  else if (idx < 1179648)  { W = mlp_w1; O = w1; K = 384;  N = 1536; loc = idx - 589824; }
  else if (idx < 1769472)  { W = mlp_w2; O = w2; K = 1536; N = 384;  loc = idx - 1179648; }
  else return;
  int n = loc / K, k = loc - n * K;
  bf16 h = f2b(W[(size_t)k * N + n]);
  O[loc] = *(ushort_t*)&h;
}

// ---------------- LN1 + cyclic shift(-3,+3) + window partition (full) ----------------
__global__ __launch_bounds__(64) void ln1_kernel(const float* __restrict__ x,
                                                 const float* __restrict__ g,
                                                 const float* __restrict__ bta,
                                                 bf16* __restrict__ wins) {
  int t = blockIdx.x;
  int lane = threadIdx.x;
  int w = t / 49, n = t - w * 49;
  int bi = w >> 6, wi = w & 63;
  int hw = wi >> 3, ww = wi & 7;
  int ti = n / 7, tj = n - ti * 7;
  int hr = hw * 7 + ti, wr = ww * 7 + tj;
  int hs = (hr + 3) % 56;          // roll -3 on h
  int wsc = (wr + 53) % 56;        // roll +3 on w
  const float* row = x + ((size_t)bi * 3136 + hs * 56 + wsc) * 384;
  float v[6];
  float s = 0.f, s2 = 0.f;
#pragma unroll
  for (int j = 0; j < 6; ++j) {
    v[j] = row[lane + 64 * j];
    s += v[j]; s2 += v[j] * v[j];
  }
#pragma unroll
  for (int m = 32; m >= 1; m >>= 1) {
    s  += __shfl_xor(s, m, 64);
    s2 += __shfl_xor(s2, m, 64);
  }
  float mu = s * (1.f / 384.f);
  float var = s2 * (1.f / 384.f) - mu * mu;
  float rstd = rsqrtf(var + 1e-3f);
  bf16* orow = wins + (size_t)t * 384;
#pragma unroll
  for (int j = 0; j < 6; ++j) {
    int c = lane + 64 * j;
    orow[c] = f2b((v[j] - mu) * rstd * g[c] + bta[c]);
  }
}

// ---------------- LN2: fp32 rows -> bf16 ----------------
__global__ __launch_bounds__(64) void ln2_kernel(const float* __restrict__ x1,
                                                 const float* __restrict__ g,
                                                 const float* __restrict__ bta,
                                                 bf16* __restrict__ out) {
  int t = blockIdx.x;
  int lane = threadIdx.x;
  const float* row = x1 + (size_t)t * 384;
  float v[6];
  float s = 0.f, s2 = 0.f;
#pragma unroll
  for (int j = 0; j < 6; ++j) {
    v[j] = row[lane + 64 * j];
    s += v[j]; s2 += v[j] * v[j];
  }
#pragma unroll
  for (int m = 32; m >= 1; m >>= 1) {
    s  += __shfl_xor(s, m, 64);
    s2 += __shfl_xor(s2, m, 64);
  }
  float mu = s * (1.f / 384.f);
  float var = s2 * (1.f / 384.f) - mu * mu;
  float rstd = rsqrtf(var + 1e-3f);
  bf16* orow = out + (size_t)t * 384;
#pragma unroll
  for (int j = 0; j < 6; ++j) {
    int c = lane + 64 * j;
    orow[c] = f2b((v[j] - mu) * rstd * g[c] + bta[c]);
  }
}

// ---------------- MFMA GEMM: r7 loop + R=2 row-tiles per block ----------------
// Theory (r9 post-mortem): MfmaUtil(15.5%) x dur == the MFMA-pipe floor, so the
// gap is unamortized per-block overhead (12 tiles x 8 MFMA per block). R=2:
// block computes 256x128 output (2 row-tiles), sharing the B staging and b-frags
// across both. Halves blocks & barriers per MFMA; ds_read/MFMA 0.75 -> 0.5.
// Envelope kept: acc 64 + frags ~110 VGPR (<=128 -> 4 waves/SIMD), LDS 24KB ->
// 2 blocks/CU = 16 waves (r7-proven TLP). Swizzles proven (0 conflicts, ideal
// FETCH). Epilogue = r7 direct stores (beat r9's LDS-staged variant).
template<int MODE>
__global__ __launch_bounds__(512, 4) void mfma_gemm(
    const ushort_t* __restrict__ A, const ushort_t* __restrict__ Bt,
    const float* __restrict__ bias, int N, int K,
    const float* __restrict__ resid, void* __restrict__ out_) {
  __shared__ ushort_t As[2][128 * 32];    // [rt][128 rows][32 k]
  __shared__ ushort_t Bs[128 * 32];
  int tid = threadIdx.x;
  int lane = tid & 63, wv = tid >> 6;     // 8 waves
  int wm = wv >> 1, wn = wv & 1;          // 4M x 2N wave grid; wave tile 32x64
  int lm = lane & 15, kg = lane >> 4;

  // XCD-chunked bijective swizzle (m204)
  int nwg = gridDim.x;
  int q = nwg >> 3, r = nwg & 7;
  int xcd = blockIdx.x & 7, ii = blockIdx.x >> 3;
  int l = ((xcd < r) ? xcd * (q + 1) : r * (q + 1) + (xcd - r) * q) + ii;
  int nxt = N >> 7;
  int col0 = (l % nxt) * 128, row0 = (l / nxt) * 256;

  f32x4 acc[2][2][4];                     // [rt][i][j]
#pragma unroll
  for (int rt = 0; rt < 2; ++rt)
#pragma unroll
    for (int i = 0; i < 2; ++i)
#pragma unroll
      for (int j = 0; j < 4; ++j) acc[rt][i][j] = (f32x4){0.f, 0.f, 0.f, 0.f};

  int rsub = lane >> 2;                     // 0..15: row within 16-row chunk
  int bsrc = (lane & 3) ^ ((rsub >> 1) & 3);  // inverse-swizzled source block
  int pbr = kg ^ ((lm >> 1) & 3);           // read: physical block for logical kg

  const ushort_t* gA0 = &A[(size_t)(row0 + wv * 16 + rsub) * K + bsrc * 8];
  const ushort_t* gA1 = gA0 + (size_t)128 * K;
  const ushort_t* gB  = &Bt[(size_t)(col0 + wv * 16 + rsub) * K + bsrc * 8];

  int NT = K >> 5;
  for (int t = 0; t < NT; ++t) {
    __builtin_amdgcn_global_load_lds(
        (const __attribute__((address_space(1))) void*)(gA0 + (t << 5)),
        (__attribute__((address_space(3))) void*)&As[0][wv * 512], 16, 0, 0);
    __builtin_amdgcn_global_load_lds(
        (const __attribute__((address_space(1))) void*)(gA1 + (t << 5)),
        (__attribute__((address_space(3))) void*)&As[1][wv * 512], 16, 0, 0);
    __builtin_amdgcn_global_load_lds(
        (const __attribute__((address_space(1))) void*)(gB + (t << 5)),
        (__attribute__((address_space(3))) void*)&Bs[wv * 512], 16, 0, 0);
    __syncthreads();
    bf16x8 b[4];
#pragma unroll
    for (int j = 0; j < 4; ++j) {
      int rb = wn * 64 + j * 16 + lm;
      b[j] = *(const bf16x8*)&Bs[rb * 32 + pbr * 8];
    }
#pragma unroll
    for (int rt = 0; rt < 2; ++rt) {
      bf16x8 a[2];
#pragma unroll
      for (int i = 0; i < 2; ++i) {
        int ra = wm * 32 + i * 16 + lm;
        a[i] = *(const bf16x8*)&As[rt][ra * 32 + pbr * 8];
      }
#pragma unroll
      for (int i = 0; i < 2; ++i)
#pragma unroll
        for (int j = 0; j < 4; ++j)
          acc[rt][i][j] = __builtin_amdgcn_mfma_f32_16x16x32_bf16(a[i], b[j], acc[rt][i][j], 0, 0, 0);
    }
    __syncthreads();
  }

  int n0 = col0 + wn * 64;
#pragma unroll
  for (int rt = 0; rt < 2; ++rt) {
    int m0 = row0 + rt * 128 + wm * 32;
#pragma unroll
    for (int i = 0; i < 2; ++i) {
#pragma unroll
      for (int reg = 0; reg < 4; ++reg) {
        int m = m0 + i * 16 + kg * 4 + reg;
        size_t obase = 0;
        if (MODE == 1) {
          int w = m / 49, nn = m - w * 49;
          int bi = w >> 6, wi = w & 63;
          int hw = wi >> 3, ww = wi & 7;
          int ti = nn / 7, tj = nn - ti * 7;
          int hf = (hw * 7 + ti + 3) % 56, wf = (ww * 7 + tj + 3) % 56;
          obase = ((size_t)bi * 3136 + hf * 56 + wf) * 384;
        }
#pragma unroll
        for (int j = 0; j < 4; ++j) {
          int cN = n0 + j * 16 + lm;
          float v = acc[rt][i][j][reg] + bias[cN];
          if (MODE == 0) {
            ((bf16*)out_)[(size_t)m * N + cN] = f2b(v);
          } else if (MODE == 1) {
            float* O = (float*)out_;
            O[obase + cN] = v + resid[obase + cN];
          } else if (MODE == 2) {
            ((bf16*)out_)[(size_t)m * N + cN] = f2b(gelu_f(v));
          } else {
            float* O = (float*)out_;
            O[(size_t)m * N + cN] = v + resid[(size_t)m * N + cN];
          }
        }
      }
    }
  }
}

// ---------------- MFMA attention: block = (window, head-group of 3) ----------------
// Per head: QK^T (4 mfma/wave), in-register softmax (+bias+mask), P->LDS, PV (4 mfma/wave).
__global__ __launch_bounds__(256) void attn_mfma(const ushort_t* __restrict__ qkv_c,
                                                 const float* __restrict__ table,
                                                 ushort_t* __restrict__ attn_c,
                                                 int w_base) {
  int wl = blockIdx.x >> 2, hg = blockIdx.x & 3;   // 512 windows x 4 head-groups
  int w = w_base + wl;
  int wi = w & 63;
  int hw = wi >> 3, ww = wi & 7;
  __shared__ ushort_t Qs[64 * 40];   // [row m][d], stride 40 (16B-aligned rows)
  __shared__ ushort_t Ks[64 * 40];   // [row n][d]
  __shared__ ushort_t Vt[32 * 72];   // [dcol][key], stride 72
  __shared__ ushort_t Ps[64 * 72];   // [row m][key], stride 72
  __shared__ float bias_s[169 * 12];
  int tid = threadIdx.x;
  int lane = tid & 63, wv = tid >> 6;              // wv = 16-row strip
  int lm = lane & 15, kg = lane >> 4;

  // zero-fill staging pads once (rows/cols >= 49 stay zero across heads)
  for (int i = tid; i < 64 * 40; i += 256) { Qs[i] = 0; Ks[i] = 0; }
  for (int i = tid; i < 32 * 72; i += 256) Vt[i] = 0;
  for (int i = tid; i < 169 * 12; i += 256) bias_s[i] = table[i];
  __syncthreads();

  for (int hh = 0; hh < 3; ++hh) {
    int h = hg * 3 + hh;
    // stage Q,K,V(transposed) for this head: 392 vec4 jobs
    const ushort_t* base = qkv_c + (size_t)wl * 49 * 1152 + h * 32;
    for (int idx = tid; idx < 392; idx += 256) {
      int n = idx >> 3, d0 = (idx & 7) * 4;
      const ushort_t* p = base + (size_t)n * 1152 + d0;
      ushort4 q = *(const ushort4*)(p);
      ushort4 k = *(const ushort4*)(p + 384);
      ushort4 v = *(const ushort4*)(p + 768);
      *(ushort4*)&Qs[n * 40 + d0] = q;
      *(ushort4*)&Ks[n * 40 + d0] = k;
      Vt[(d0 + 0) * 72 + n] = v.x;
      Vt[(d0 + 1) * 72 + n] = v.y;
      Vt[(d0 + 2) * 72 + n] = v.z;
      Vt[(d0 + 3) * 72 + n] = v.w;
    }
    __syncthreads();

    // QK^T: wave's 16-row strip x 64 cols
    bf16x8 qa = *(const bf16x8*)&Qs[(wv * 16 + lm) * 40 + kg * 8];
    f32x4 sacc[4];
#pragma unroll
    for (int jt = 0; jt < 4; ++jt) {
      bf16x8 kb = *(const bf16x8*)&Ks[(jt * 16 + lm) * 40 + kg * 8];
      sacc[jt] = __builtin_amdgcn_mfma_f32_16x16x32_bf16(
          qa, kb, (f32x4){0.f, 0.f, 0.f, 0.f}, 0, 0, 0);
    }

    // softmax rows: row = wv*16 + kg*4 + reg, col = jt*16 + lm
    int i_base = wv * 16 + kg * 4;
#pragma unroll
    for (int reg = 0; reg < 4; ++reg) {
      int i = i_base + reg;
      int ii = (i < 49) ? i : 0;
      int yi = ii / 7, xi = ii - yi * 7;
      int hri = hw * 7 + yi, wri = ww * 7 + xi;
      int ri = (hri < 49 ? 0 : (hri < 53 ? 1 : 2)) * 3 + (wri < 49 ? 0 : (wri < 53 ? 1 : 2));
      float sv[4];
      float mx = -1e30f;
#pragma unroll
      for (int jt = 0; jt < 4; ++jt) {
        int j = jt * 16 + lm;
        int jj = (j < 49) ? j : 0;
        int yj = jj / 7, xj = jj - yj * 7;
        int hrj = hw * 7 + yj, wrj = ww * 7 + xj;
        int rj = (hrj < 49 ? 0 : (hrj < 53 ? 1 : 2)) * 3 + (wrj < 49 ? 0 : (wrj < 53 ? 1 : 2));
        int ridx = (yi - yj + 6) * 13 + (xi - xj + 6);
        float s = sacc[jt][reg] * SCALE_ + bias_s[ridx * 12 + h] + ((ri == rj) ? 0.f : -100.f);
        sv[jt] = (j < 49) ? s : -1e30f;
        mx = fmaxf(mx, sv[jt]);
      }
#pragma unroll
      for (int msk = 1; msk < 16; msk <<= 1) mx = fmaxf(mx, __shfl_xor(mx, msk, 64));
      float sm = 0.f;
#pragma unroll
      for (int jt = 0; jt < 4; ++jt) {
        float e = ((jt * 16 + lm) < 49) ? __expf(sv[jt] - mx) : 0.f;
        sv[jt] = e; sm += e;
      }
#pragma unroll
      for (int msk = 1; msk < 16; msk <<= 1) sm += __shfl_xor(sm, msk, 64);
      float inv = 1.f / sm;   // sm >= 1 (max-subtracted; every row has >=1 valid col)
#pragma unroll
      for (int jt = 0; jt < 4; ++jt) {
        bf16 pb = f2b(sv[jt] * inv);
        Ps[(size_t)i * 72 + jt * 16 + lm] = *(ushort_t*)&pb;
      }
    }
    // PV: O_strip[16][32] = P_strip[16][64] @ V[64][32] (own strip only -> no barrier)
    f32x4 oacc[2] = {(f32x4){0.f, 0.f, 0.f, 0.f}, (f32x4){0.f, 0.f, 0.f, 0.f}};
#pragma unroll
    for (int ks = 0; ks < 2; ++ks) {
      bf16x8 pa = *(const bf16x8*)&Ps[(wv * 16 + lm) * 72 + ks * 32 + kg * 8];
#pragma unroll
      for (int dt = 0; dt < 2; ++dt) {
        bf16x8 vb = *(const bf16x8*)&Vt[(dt * 16 + lm) * 72 + ks * 32 + kg * 8];
        oacc[dt] = __builtin_amdgcn_mfma_f32_16x16x32_bf16(pa, vb, oacc[dt], 0, 0, 0);
      }
    }
#pragma unroll
    for (int reg = 0; reg < 4; ++reg) {
      int r = i_base + reg;
      if (r < 49) {
#pragma unroll
        for (int dt = 0; dt < 2; ++dt) {
          bf16 ob = f2b(oacc[dt][reg]);
          attn_c[((size_t)wl * 49 + r) * 384 + h * 32 + dt * 16 + lm] = *(ushort_t*)&ob;
        }
      }
    }
    __syncthreads();   // protect Qs/Ks/Vt before next head's restage
  }
}

extern "C" void kernel_launch(void* const* d_in, const int* in_sizes, int n_in,
                              void* d_out, int out_size, void* d_ws, size_t ws_size,
                              hipStream_t stream) {
  const float* x      = (const float*)d_in[0];
  const float* ln1_g  = (const float*)d_in[1];
  const float* ln1_b  = (const float*)d_in[2];
  const float* ln2_g  = (const float*)d_in[3];
  const float* ln2_b  = (const float*)d_in[4];
  const float* qkv_w  = (const float*)d_in[5];
  const float* qkv_b  = (const float*)d_in[6];
  const float* proj_w = (const float*)d_in[7];
  const float* proj_b = (const float*)d_in[8];
  const float* mlp_w1 = (const float*)d_in[9];
  const float* mlp_b1 = (const float*)d_in[10];
  const float* mlp_w2 = (const float*)d_in[11];
  const float* mlp_b2 = (const float*)d_in[12];
  const float* rel_tb = (const float*)d_in[13];

  char* ws = (char*)d_ws;
  ushort_t* r0 = (ushort_t*)(ws + 0);                  // 38.5MB: wins / attn_out / ln2o
  ushort_t* r1 = (ushort_t*)(ws + 38535168ull);        // 77MB: qkv chunk / hidden chunk
  ushort_t* wq = (ushort_t*)(ws + 115605504ull);       // bf16 W^T: [1152,384]
  ushort_t* wp = wq + 442368;                          // [384,384]
  ushort_t* w1 = wp + 147456;                          // [1536,384]
  ushort_t* w2 = w1 + 589824;                          // [384,1536]
  float* out = (float*)d_out;

  wt_all<<<6912, 256, 0, stream>>>(qkv_w, proj_w, mlp_w1, mlp_w2, wq, wp, w1, w2);

  ln1_kernel<<<TOKENS, 64, 0, stream>>>(x, ln1_g, ln1_b, (bf16*)r0);

  for (int c = 0; c < 2; ++c) {
    ushort_t* winc = r0 + (size_t)c * CROWS2 * 384;
    mfma_gemm<0><<<(CROWS2 / 256) * 9, 512, 0, stream>>>(
        winc, wq, qkv_b, 1152, 384, nullptr, (void*)r1);
    attn_mfma<<<CW2 * 4, 256, 0, stream>>>(r1, rel_tb, winc, c * CW2);
  }

  mfma_gemm<1><<<(TOKENS / 256) * 3, 512, 0, stream>>>(
      r0, wp, proj_b, 384, 384, x, (void*)out);

  ln2_kernel<<<TOKENS, 64, 0, stream>>>(out, ln2_g, ln2_b, (bf16*)r0);

  for (int c = 0; c < 2; ++c) {
    ushort_t* lc = r0 + (size_t)c * CROWS2 * 384;
    float* oc = out + (size_t)c * CROWS2 * 384;
    mfma_gemm<2><<<(CROWS2 / 256) * 12, 512, 0, stream>>>(
        lc, w1, mlp_b1, 1536, 384, nullptr, (void*)r1);
    mfma_gemm<3><<<(CROWS2 / 256) * 3, 512, 0, stream>>>(
        r1, w2, mlp_b2, 384, 1536, oc, (void*)oc);
  }
}

// Round 12
// 596.537 us; speedup vs baseline: 1.0350x; 1.0350x over previous
//
#include <hip/hip_runtime.h>
#include <hip/hip_bf16.h>
#include <math.h>

typedef __hip_bfloat16 bf16;
typedef unsigned short ushort_t;
typedef __bf16 bf16x8 __attribute__((ext_vector_type(8)));
typedef float f32x4 __attribute__((ext_vector_type(4)));

#define TOKENS 50176        // 16 * 3136
#define CW2 512             // windows per chunk (2 chunks)
#define CROWS2 (CW2 * 49)   // 25088 rows per chunk
#define SCALE_ 0.17677669529663687f  // 32^-0.5

__device__ __forceinline__ float b2f(bf16 v) { return __bfloat162float(v); }
__device__ __forceinline__ bf16  f2b(float v) { return __float2bfloat16(v); }

// fast erf-GELU: Abramowitz-Stegun 7.1.26, |err| <= 1.5e-7 (below bf16 rounding)
__device__ __forceinline__ float gelu_f(float v) {
  float x = v * 0.7071067811865475f;
  float ax = fabsf(x);
  float t = 1.f / (1.f + 0.3275911f * ax);
  float poly = ((((1.061405429f * t - 1.453152027f) * t + 1.421413741f) * t
                 - 0.284496736f) * t + 0.254829592f) * t;
  float erfv = 1.f - poly * __expf(-ax * ax);
  erfv = copysignf(erfv, x);
  return 0.5f * v * (1.f + erfv);
}

// ---------------- weight convert: all 4 weights in ONE dispatch ----------------
__global__ __launch_bounds__(256) void wt_all(const float* __restrict__ qkv_w,
                                              const float* __restrict__ proj_w,
                                              const float* __restrict__ mlp_w1,
                                              const float* __restrict__ mlp_w2,
                                              ushort_t* __restrict__ wq,
                                              ushort_t* __restrict__ wp,
                                              ushort_t* __restrict__ w1,
                                              ushort_t* __restrict__ w2) {
  int idx = blockIdx.x * 256 + threadIdx.x;
  const float* W; ushort_t* O; int K, N, loc;
  if (idx < 442368)        { W = qkv_w;  O = wq; K = 384;  N = 1152; loc = idx; }
  else if (idx < 589824)   { W = proj_w; O = wp; K = 384;  N = 384;  loc = idx - 442368; }
  else if (idx < 1179648)  { W = mlp_w1; O = w1; K = 384;  N = 1536; loc = idx - 589824; }
  else if (idx < 1769472)  { W = mlp_w2; O = w2; K = 1536; N = 384;  loc = idx - 1179648; }
  else return;
  int n = loc / K, k = loc - n * K;
  bf16 h = f2b(W[(size_t)k * N + n]);
  O[loc] = *(ushort_t*)&h;
}

// ---------------- LN1 + cyclic shift(-3,+3) + window partition (full) ----------------
__global__ __launch_bounds__(64) void ln1_kernel(const float* __restrict__ x,
                                                 const float* __restrict__ g,
                                                 const float* __restrict__ bta,
                                                 bf16* __restrict__ wins) {
  int t = blockIdx.x;
  int lane = threadIdx.x;
  int w = t / 49, n = t - w * 49;
  int bi = w >> 6, wi = w & 63;
  int hw = wi >> 3, ww = wi & 7;
  int ti = n / 7, tj = n - ti * 7;
  int hr = hw * 7 + ti, wr = ww * 7 + tj;
  int hs = (hr + 3) % 56;          // roll -3 on h
  int wsc = (wr + 53) % 56;        // roll +3 on w
  const float* row = x + ((size_t)bi * 3136 + hs * 56 + wsc) * 384;
  float v[6];
  float s = 0.f, s2 = 0.f;
#pragma unroll
  for (int j = 0; j < 6; ++j) {
    v[j] = row[lane + 64 * j];
    s += v[j]; s2 += v[j] * v[j];
  }
#pragma unroll
  for (int m = 32; m >= 1; m >>= 1) {
    s  += __shfl_xor(s, m, 64);
    s2 += __shfl_xor(s2, m, 64);
  }
  float mu = s * (1.f / 384.f);
  float var = s2 * (1.f / 384.f) - mu * mu;
  float rstd = rsqrtf(var + 1e-3f);
  bf16* orow = wins + (size_t)t * 384;
#pragma unroll
  for (int j = 0; j < 6; ++j) {
    int c = lane + 64 * j;
    orow[c] = f2b((v[j] - mu) * rstd * g[c] + bta[c]);
  }
}

// ---------------- LN2: fp32 rows -> bf16 ----------------
__global__ __launch_bounds__(64) void ln2_kernel(const float* __restrict__ x1,
                                                 const float* __restrict__ g,
                                                 const float* __restrict__ bta,
                                                 bf16* __restrict__ out) {
  int t = blockIdx.x;
  int lane = threadIdx.x;
  const float* row = x1 + (size_t)t * 384;
  float v[6];
  float s = 0.f, s2 = 0.f;
#pragma unroll
  for (int j = 0; j < 6; ++j) {
    v[j] = row[lane + 64 * j];
    s += v[j]; s2 += v[j] * v[j];
  }
#pragma unroll
  for (int m = 32; m >= 1; m >>= 1) {
    s  += __shfl_xor(s, m, 64);
    s2 += __shfl_xor(s2, m, 64);
  }
  float mu = s * (1.f / 384.f);
  float var = s2 * (1.f / 384.f) - mu * mu;
  float rstd = rsqrtf(var + 1e-3f);
  bf16* orow = out + (size_t)t * 384;
#pragma unroll
  for (int j = 0; j < 6; ++j) {
    int c = lane + 64 * j;
    orow[c] = f2b((v[j] - mu) * rstd * g[c] + bta[c]);
  }
}

// ---------------- MFMA GEMM: r7 structure (best measured: 600us total) ----------------
// 128x128 tile, 8 waves (wave-tile 32x64), BK=32 single-buffer, 16.25KB LDS,
// high TLP. Only change vs r7: __launch_bounds__(512, 8) -- declare 4 blocks/CU
// (32 waves) as the floor; VGPR=36/LDS=16.25KB impose no resource cap, r7's
// measured occupancy 52% may have been capped by the (512,6) declaration.
// Swizzle/addressing proven (0 bank conflicts, ideal FETCH):
//   phys 16B block p at row r holds logical p ^ ((r>>1)&3); linear LDS dest via
//   global_load_lds; read p = kg ^ ((lm>>1)&3).
// Grid: 1-D, m204 bijective XCD-chunked swizzle, row-panel-major.
template<int MODE>
__global__ __launch_bounds__(512, 8) void mfma_gemm(
    const ushort_t* __restrict__ A, const ushort_t* __restrict__ Bt,
    const float* __restrict__ bias, int N, int K,
    const float* __restrict__ resid, void* __restrict__ out_) {
  __shared__ ushort_t As[128 * 32];
  __shared__ ushort_t Bs[128 * 32];
  int tid = threadIdx.x;
  int lane = tid & 63, wv = tid >> 6;     // 8 waves
  int wm = wv >> 1, wn = wv & 1;          // 4M x 2N wave grid; wave tile 32x64
  int lm = lane & 15, kg = lane >> 4;

  // XCD-chunked bijective swizzle (m204)
  int nwg = gridDim.x;
  int q = nwg >> 3, r = nwg & 7;
  int xcd = blockIdx.x & 7, ii = blockIdx.x >> 3;
  int l = ((xcd < r) ? xcd * (q + 1) : r * (q + 1) + (xcd - r) * q) + ii;
  int nxt = N >> 7;
  int col0 = (l % nxt) * 128, row0 = (l / nxt) * 128;

  f32x4 acc[2][4];
#pragma unroll
  for (int i = 0; i < 2; ++i)
#pragma unroll
    for (int j = 0; j < 4; ++j) acc[i][j] = (f32x4){0.f, 0.f, 0.f, 0.f};

  int rsub = lane >> 2;                     // 0..15: row within 16-row chunk
  int bsrc = (lane & 3) ^ ((rsub >> 1) & 3);  // inverse-swizzled source block
  int pbr = kg ^ ((lm >> 1) & 3);           // read: physical block for logical kg

  const ushort_t* gA = &A[(size_t)(row0 + wv * 16 + rsub) * K + bsrc * 8];
  const ushort_t* gB = &Bt[(size_t)(col0 + wv * 16 + rsub) * K + bsrc * 8];

  int NT = K >> 5;
  for (int t = 0; t < NT; ++t) {
    __builtin_amdgcn_global_load_lds(
        (const __attribute__((address_space(1))) void*)(gA + (t << 5)),
        (__attribute__((address_space(3))) void*)&As[wv * 512], 16, 0, 0);
    __builtin_amdgcn_global_load_lds(
        (const __attribute__((address_space(1))) void*)(gB + (t << 5)),
        (__attribute__((address_space(3))) void*)&Bs[wv * 512], 16, 0, 0);
    __syncthreads();
    bf16x8 a[2], b[4];
#pragma unroll
    for (int i = 0; i < 2; ++i) {
      int ra = wm * 32 + i * 16 + lm;
      a[i] = *(const bf16x8*)&As[ra * 32 + pbr * 8];
    }
#pragma unroll
    for (int j = 0; j < 4; ++j) {
      int rb = wn * 64 + j * 16 + lm;
      b[j] = *(const bf16x8*)&Bs[rb * 32 + pbr * 8];
    }
#pragma unroll
    for (int i = 0; i < 2; ++i)
#pragma unroll
      for (int j = 0; j < 4; ++j)
        acc[i][j] = __builtin_amdgcn_mfma_f32_16x16x32_bf16(a[i], b[j], acc[i][j], 0, 0, 0);
    __syncthreads();
  }

  int m0 = row0 + wm * 32, n0 = col0 + wn * 64;
#pragma unroll
  for (int i = 0; i < 2; ++i) {
#pragma unroll
    for (int reg = 0; reg < 4; ++reg) {
      int m = m0 + i * 16 + kg * 4 + reg;
      size_t obase = 0;
      if (MODE == 1) {
        int w = m / 49, nn = m - w * 49;
        int bi = w >> 6, wi = w & 63;
        int hw = wi >> 3, ww = wi & 7;
        int ti = nn / 7, tj = nn - ti * 7;
        int hf = (hw * 7 + ti + 3) % 56, wf = (ww * 7 + tj + 3) % 56;
        obase = ((size_t)bi * 3136 + hf * 56 + wf) * 384;
      }
#pragma unroll
      for (int j = 0; j < 4; ++j) {
        int cN = n0 + j * 16 + lm;
        float v = acc[i][j][reg] + bias[cN];
        if (MODE == 0) {
          ((bf16*)out_)[(size_t)m * N + cN] = f2b(v);
        } else if (MODE == 1) {
          float* O = (float*)out_;
          O[obase + cN] = v + resid[obase + cN];
        } else if (MODE == 2) {
          ((bf16*)out_)[(size_t)m * N + cN] = f2b(gelu_f(v));
        } else {
          float* O = (float*)out_;
          O[(size_t)m * N + cN] = v + resid[(size_t)m * N + cN];
        }
      }
    }
  }
}

// ---------------- MFMA attention: block = (window, head-group of 3) ----------------
// Per head: QK^T (4 mfma/wave), in-register softmax (+bias+mask), P->LDS, PV (4 mfma/wave).
__global__ __launch_bounds__(256) void attn_mfma(const ushort_t* __restrict__ qkv_c,
                                                 const float* __restrict__ table,
                                                 ushort_t* __restrict__ attn_c,
                                                 int w_base) {
  int wl = blockIdx.x >> 2, hg = blockIdx.x & 3;   // 512 windows x 4 head-groups
  int w = w_base + wl;
  int wi = w & 63;
  int hw = wi >> 3, ww = wi & 7;
  __shared__ ushort_t Qs[64 * 40];   // [row m][d], stride 40 (16B-aligned rows)
  __shared__ ushort_t Ks[64 * 40];   // [row n][d]
  __shared__ ushort_t Vt[32 * 72];   // [dcol][key], stride 72
  __shared__ ushort_t Ps[64 * 72];   // [row m][key], stride 72
  __shared__ float bias_s[169 * 12];
  int tid = threadIdx.x;
  int lane = tid & 63, wv = tid >> 6;              // wv = 16-row strip
  int lm = lane & 15, kg = lane >> 4;

  // zero-fill staging pads once (rows/cols >= 49 stay zero across heads)
  for (int i = tid; i < 64 * 40; i += 256) { Qs[i] = 0; Ks[i] = 0; }
  for (int i = tid; i < 32 * 72; i += 256) Vt[i] = 0;
  for (int i = tid; i < 169 * 12; i += 256) bias_s[i] = table[i];
  __syncthreads();

  for (int hh = 0; hh < 3; ++hh) {
    int h = hg * 3 + hh;
    // stage Q,K,V(transposed) for this head: 392 vec4 jobs
    const ushort_t* base = qkv_c + (size_t)wl * 49 * 1152 + h * 32;
    for (int idx = tid; idx < 392; idx += 256) {
      int n = idx >> 3, d0 = (idx & 7) * 4;
      const ushort_t* p = base + (size_t)n * 1152 + d0;
      ushort4 q = *(const ushort4*)(p);
      ushort4 k = *(const ushort4*)(p + 384);
      ushort4 v = *(const ushort4*)(p + 768);
      *(ushort4*)&Qs[n * 40 + d0] = q;
      *(ushort4*)&Ks[n * 40 + d0] = k;
      Vt[(d0 + 0) * 72 + n] = v.x;
      Vt[(d0 + 1) * 72 + n] = v.y;
      Vt[(d0 + 2) * 72 + n] = v.z;
      Vt[(d0 + 3) * 72 + n] = v.w;
    }
    __syncthreads();

    // QK^T: wave's 16-row strip x 64 cols
    bf16x8 qa = *(const bf16x8*)&Qs[(wv * 16 + lm) * 40 + kg * 8];
    f32x4 sacc[4];
#pragma unroll
    for (int jt = 0; jt < 4; ++jt) {
      bf16x8 kb = *(const bf16x8*)&Ks[(jt * 16 + lm) * 40 + kg * 8];
      sacc[jt] = __builtin_amdgcn_mfma_f32_16x16x32_bf16(
          qa, kb, (f32x4){0.f, 0.f, 0.f, 0.f}, 0, 0, 0);
    }

    // softmax rows: row = wv*16 + kg*4 + reg, col = jt*16 + lm
    int i_base = wv * 16 + kg * 4;
#pragma unroll
    for (int reg = 0; reg < 4; ++reg) {
      int i = i_base + reg;
      int ii = (i < 49) ? i : 0;
      int yi = ii / 7, xi = ii - yi * 7;
      int hri = hw * 7 + yi, wri = ww * 7 + xi;
      int ri = (hri < 49 ? 0 : (hri < 53 ? 1 : 2)) * 3 + (wri < 49 ? 0 : (wri < 53 ? 1 : 2));
      float sv[4];
      float mx = -1e30f;
#pragma unroll
      for (int jt = 0; jt < 4; ++jt) {
        int j = jt * 16 + lm;
        int jj = (j < 49) ? j : 0;
        int yj = jj / 7, xj = jj - yj * 7;
        int hrj = hw * 7 + yj, wrj = ww * 7 + xj;
        int rj = (hrj < 49 ? 0 : (hrj < 53 ? 1 : 2)) * 3 + (wrj < 49 ? 0 : (wrj < 53 ? 1 : 2));
        int ridx = (yi - yj + 6) * 13 + (xi - xj + 6);
        float s = sacc[jt][reg] * SCALE_ + bias_s[ridx * 12 + h] + ((ri == rj) ? 0.f : -100.f);
        sv[jt] = (j < 49) ? s : -1e30f;
        mx = fmaxf(mx, sv[jt]);
      }
#pragma unroll
      for (int msk = 1; msk < 16; msk <<= 1) mx = fmaxf(mx, __shfl_xor(mx, msk, 64));
      float sm = 0.f;
#pragma unroll
      for (int jt = 0; jt < 4; ++jt) {
        float e = ((jt * 16 + lm) < 49) ? __expf(sv[jt] - mx) : 0.f;
        sv[jt] = e; sm += e;
      }
#pragma unroll
      for (int msk = 1; msk < 16; msk <<= 1) sm += __shfl_xor(sm, msk, 64);
      float inv = 1.f / sm;   // sm >= 1 (max-subtracted; every row has >=1 valid col)
#pragma unroll
      for (int jt = 0; jt < 4; ++jt) {
        bf16 pb = f2b(sv[jt] * inv);
        Ps[(size_t)i * 72 + jt * 16 + lm] = *(ushort_t*)&pb;
      }
    }
    // PV: O_strip[16][32] = P_strip[16][64] @ V[64][32] (own strip only -> no barrier)
    f32x4 oacc[2] = {(f32x4){0.f, 0.f, 0.f, 0.f}, (f32x4){0.f, 0.f, 0.f, 0.f}};
#pragma unroll
    for (int ks = 0; ks < 2; ++ks) {
      bf16x8 pa = *(const bf16x8*)&Ps[(wv * 16 + lm) * 72 + ks * 32 + kg * 8];
#pragma unroll
      for (int dt = 0; dt < 2; ++dt) {
        bf16x8 vb = *(const bf16x8*)&Vt[(dt * 16 + lm) * 72 + ks * 32 + kg * 8];
        oacc[dt] = __builtin_amdgcn_mfma_f32_16x16x32_bf16(pa, vb, oacc[dt], 0, 0, 0);
      }
    }
#pragma unroll
    for (int reg = 0; reg < 4; ++reg) {
      int r = i_base + reg;
      if (r < 49) {
#pragma unroll
        for (int dt = 0; dt < 2; ++dt) {
          bf16 ob = f2b(oacc[dt][reg]);
          attn_c[((size_t)wl * 49 + r) * 384 + h * 32 + dt * 16 + lm] = *(ushort_t*)&ob;
        }
      }
    }
    __syncthreads();   // protect Qs/Ks/Vt before next head's restage
  }
}

extern "C" void kernel_launch(void* const* d_in, const int* in_sizes, int n_in,
                              void* d_out, int out_size, void* d_ws, size_t ws_size,
                              hipStream_t stream) {
  const float* x      = (const float*)d_in[0];
  const float* ln1_g  = (const float*)d_in[1];
  const float* ln1_b  = (const float*)d_in[2];
  const float* ln2_g  = (const float*)d_in[3];
  const float* ln2_b  = (const float*)d_in[4];
  const float* qkv_w  = (const float*)d_in[5];
  const float* qkv_b  = (const float*)d_in[6];
  const float* proj_w = (const float*)d_in[7];
  const float* proj_b = (const float*)d_in[8];
  const float* mlp_w1 = (const float*)d_in[9];
  const float* mlp_b1 = (const float*)d_in[10];
  const float* mlp_w2 = (const float*)d_in[11];
  const float* mlp_b2 = (const float*)d_in[12];
  const float* rel_tb = (const float*)d_in[13];

  char* ws = (char*)d_ws;
  ushort_t* r0 = (ushort_t*)(ws + 0);                  // 38.5MB: wins / attn_out / ln2o
  ushort_t* r1 = (ushort_t*)(ws + 38535168ull);        // 77MB: qkv chunk / hidden chunk
  ushort_t* wq = (ushort_t*)(ws + 115605504ull);       // bf16 W^T: [1152,384]
  ushort_t* wp = wq + 442368;                          // [384,384]
  ushort_t* w1 = wp + 147456;                          // [1536,384]
  ushort_t* w2 = w1 + 589824;                          // [384,1536]
  float* out = (float*)d_out;

  wt_all<<<6912, 256, 0, stream>>>(qkv_w, proj_w, mlp_w1, mlp_w2, wq, wp, w1, w2);

  ln1_kernel<<<TOKENS, 64, 0, stream>>>(x, ln1_g, ln1_b, (bf16*)r0);

  for (int c = 0; c < 2; ++c) {
    ushort_t* winc = r0 + (size_t)c * CROWS2 * 384;
    mfma_gemm<0><<<(CROWS2 / 128) * 9, 512, 0, stream>>>(
        winc, wq, qkv_b, 1152, 384, nullptr, (void*)r1);
    attn_mfma<<<CW2 * 4, 256, 0, stream>>>(r1, rel_tb, winc, c * CW2);
  }

  mfma_gemm<1><<<(TOKENS / 128) * 3, 512, 0, stream>>>(
      r0, wp, proj_b, 384, 384, x, (void*)out);

  ln2_kernel<<<TOKENS, 64, 0, stream>>>(out, ln2_g, ln2_b, (bf16*)r0);

  for (int c = 0; c < 2; ++c) {
    ushort_t* lc = r0 + (size_t)c * CROWS2 * 384;
    float* oc = out + (size_t)c * CROWS2 * 384;
    mfma_gemm<2><<<(CROWS2 / 128) * 12, 512, 0, stream>>>(
        lc, w1, mlp_b1, 1536, 384, nullptr, (void*)r1);
    mfma_gemm<3><<<(CROWS2 / 128) * 3, 512, 0, stream>>>(
        r1, w2, mlp_b2, 384, 1536, oc, (void*)oc);
  }
}

// Round 13
// 595.424 us; speedup vs baseline: 1.0370x; 1.0019x over previous
//
#include <hip/hip_runtime.h>
#include <hip/hip_bf16.h>
#include <math.h>

typedef __hip_bfloat16 bf16;
typedef unsigned short ushort_t;
typedef __bf16 bf16x8 __attribute__((ext_vector_type(8)));
typedef float f32x4 __attribute__((ext_vector_type(4)));

#define TOKENS 50176        // 16 * 3136
#define CW2 512             // windows per chunk (2 chunks)
#define CROWS2 (CW2 * 49)   // 25088 rows per chunk
#define SCALE_ 0.17677669529663687f  // 32^-0.5

__device__ __forceinline__ float b2f(bf16 v) { return __bfloat162float(v); }
__device__ __forceinline__ bf16  f2b(float v) { return __float2bfloat16(v); }

// fast erf-GELU: Abramowitz-Stegun 7.1.26, |err| <= 1.5e-7 (below bf16 rounding)
__device__ __forceinline__ float gelu_f(float v) {
  float x = v * 0.7071067811865475f;
  float ax = fabsf(x);
  float t = 1.f / (1.f + 0.3275911f * ax);
  float poly = ((((1.061405429f * t - 1.453152027f) * t + 1.421413741f) * t
                 - 0.284496736f) * t + 0.254829592f) * t;
  float erfv = 1.f - poly * __expf(-ax * ax);
  erfv = copysignf(erfv, x);
  return 0.5f * v * (1.f + erfv);
}

// ---------------- weight convert: all 4 weights in ONE dispatch ----------------
__global__ __launch_bounds__(256) void wt_all(const float* __restrict__ qkv_w,
                                              const float* __restrict__ proj_w,
                                              const float* __restrict__ mlp_w1,
                                              const float* __restrict__ mlp_w2,
                                              ushort_t* __restrict__ wq,
                                              ushort_t* __restrict__ wp,
                                              ushort_t* __restrict__ w1,
                                              ushort_t* __restrict__ w2) {
  int idx = blockIdx.x * 256 + threadIdx.x;
  const float* W; ushort_t* O; int K, N, loc;
  if (idx < 442368)        { W = qkv_w;  O = wq; K = 384;  N = 1152; loc = idx; }
  else if (idx < 589824)   { W = proj_w; O = wp; K = 384;  N = 384;  loc = idx - 442368; }
  else if (idx < 1179648)  { W = mlp_w1; O = w1; K = 384;  N = 1536; loc = idx - 589824; }
  else if (idx < 1769472)  { W = mlp_w2; O = w2; K = 1536; N = 384;  loc = idx - 1179648; }
  else return;
  int n = loc / K, k = loc - n * K;
  bf16 h = f2b(W[(size_t)k * N + n]);
  O[loc] = *(ushort_t*)&h;
}

// ---------------- LN1 + shift + window partition: 4 rows per 256-thr block ----------------
__global__ __launch_bounds__(256) void ln1_kernel(const float* __restrict__ x,
                                                  const float* __restrict__ g,
                                                  const float* __restrict__ bta,
                                                  bf16* __restrict__ wins) {
  int t = blockIdx.x * 4 + (threadIdx.x >> 6);
  int lane = threadIdx.x & 63;
  int w = t / 49, n = t - w * 49;
  int bi = w >> 6, wi = w & 63;
  int hw = wi >> 3, ww = wi & 7;
  int ti = n / 7, tj = n - ti * 7;
  int hr = hw * 7 + ti, wr = ww * 7 + tj;
  int hs = (hr + 3) % 56;          // roll -3 on h
  int wsc = (wr + 53) % 56;        // roll +3 on w
  const float* row = x + ((size_t)bi * 3136 + hs * 56 + wsc) * 384;
  float2 v[3];
  float s = 0.f, s2 = 0.f;
#pragma unroll
  for (int j = 0; j < 3; ++j) {
    v[j] = *(const float2*)&row[j * 128 + lane * 2];
    s += v[j].x + v[j].y; s2 += v[j].x * v[j].x + v[j].y * v[j].y;
  }
#pragma unroll
  for (int m = 32; m >= 1; m >>= 1) {
    s  += __shfl_xor(s, m, 64);
    s2 += __shfl_xor(s2, m, 64);
  }
  float mu = s * (1.f / 384.f);
  float var = s2 * (1.f / 384.f) - mu * mu;
  float rstd = rsqrtf(var + 1e-3f);
  ushort_t* orow = (ushort_t*)(wins + (size_t)t * 384);
#pragma unroll
  for (int j = 0; j < 3; ++j) {
    int c = j * 128 + lane * 2;
    bf16 h0 = f2b((v[j].x - mu) * rstd * g[c] + bta[c]);
    bf16 h1 = f2b((v[j].y - mu) * rstd * g[c + 1] + bta[c + 1]);
    unsigned int pk = (unsigned int)*(ushort_t*)&h0 | ((unsigned int)*(ushort_t*)&h1 << 16);
    *(unsigned int*)&orow[c] = pk;
  }
}

// ---------------- LN2: fp32 rows -> bf16, 4 rows per 256-thr block ----------------
__global__ __launch_bounds__(256) void ln2_kernel(const float* __restrict__ x1,
                                                  const float* __restrict__ g,
                                                  const float* __restrict__ bta,
                                                  bf16* __restrict__ out) {
  int t = blockIdx.x * 4 + (threadIdx.x >> 6);
  int lane = threadIdx.x & 63;
  const float* row = x1 + (size_t)t * 384;
  float2 v[3];
  float s = 0.f, s2 = 0.f;
#pragma unroll
  for (int j = 0; j < 3; ++j) {
    v[j] = *(const float2*)&row[j * 128 + lane * 2];
    s += v[j].x + v[j].y; s2 += v[j].x * v[j].x + v[j].y * v[j].y;
  }
#pragma unroll
  for (int m = 32; m >= 1; m >>= 1) {
    s  += __shfl_xor(s, m, 64);
    s2 += __shfl_xor(s2, m, 64);
  }
  float mu = s * (1.f / 384.f);
  float var = s2 * (1.f / 384.f) - mu * mu;
  float rstd = rsqrtf(var + 1e-3f);
  ushort_t* orow = (ushort_t*)(out + (size_t)t * 384);
#pragma unroll
  for (int j = 0; j < 3; ++j) {
    int c = j * 128 + lane * 2;
    bf16 h0 = f2b((v[j].x - mu) * rstd * g[c] + bta[c]);
    bf16 h1 = f2b((v[j].y - mu) * rstd * g[c + 1] + bta[c + 1]);
    unsigned int pk = (unsigned int)*(ushort_t*)&h0 | ((unsigned int)*(ushort_t*)&h1 << 16);
    *(unsigned int*)&orow[c] = pk;
  }
}

// ---------------- MFMA GEMM: r12 structure, byte-identical (best: 596.5us) ----------------
template<int MODE>
__global__ __launch_bounds__(512, 8) void mfma_gemm(
    const ushort_t* __restrict__ A, const ushort_t* __restrict__ Bt,
    const float* __restrict__ bias, int N, int K,
    const float* __restrict__ resid, void* __restrict__ out_) {
  __shared__ ushort_t As[128 * 32];
  __shared__ ushort_t Bs[128 * 32];
  int tid = threadIdx.x;
  int lane = tid & 63, wv = tid >> 6;     // 8 waves
  int wm = wv >> 1, wn = wv & 1;          // 4M x 2N wave grid; wave tile 32x64
  int lm = lane & 15, kg = lane >> 4;

  // XCD-chunked bijective swizzle (m204)
  int nwg = gridDim.x;
  int q = nwg >> 3, r = nwg & 7;
  int xcd = blockIdx.x & 7, ii = blockIdx.x >> 3;
  int l = ((xcd < r) ? xcd * (q + 1) : r * (q + 1) + (xcd - r) * q) + ii;
  int nxt = N >> 7;
  int col0 = (l % nxt) * 128, row0 = (l / nxt) * 128;

  f32x4 acc[2][4];
#pragma unroll
  for (int i = 0; i < 2; ++i)
#pragma unroll
    for (int j = 0; j < 4; ++j) acc[i][j] = (f32x4){0.f, 0.f, 0.f, 0.f};

  int rsub = lane >> 2;                     // 0..15: row within 16-row chunk
  int bsrc = (lane & 3) ^ ((rsub >> 1) & 3);  // inverse-swizzled source block
  int pbr = kg ^ ((lm >> 1) & 3);           // read: physical block for logical kg

  const ushort_t* gA = &A[(size_t)(row0 + wv * 16 + rsub) * K + bsrc * 8];
  const ushort_t* gB = &Bt[(size_t)(col0 + wv * 16 + rsub) * K + bsrc * 8];

  int NT = K >> 5;
  for (int t = 0; t < NT; ++t) {
    __builtin_amdgcn_global_load_lds(
        (const __attribute__((address_space(1))) void*)(gA + (t << 5)),
        (__attribute__((address_space(3))) void*)&As[wv * 512], 16, 0, 0);
    __builtin_amdgcn_global_load_lds(
        (const __attribute__((address_space(1))) void*)(gB + (t << 5)),
        (__attribute__((address_space(3))) void*)&Bs[wv * 512], 16, 0, 0);
    __syncthreads();
    bf16x8 a[2], b[4];
#pragma unroll
    for (int i = 0; i < 2; ++i) {
      int ra = wm * 32 + i * 16 + lm;
      a[i] = *(const bf16x8*)&As[ra * 32 + pbr * 8];
    }
#pragma unroll
    for (int j = 0; j < 4; ++j) {
      int rb = wn * 64 + j * 16 + lm;
      b[j] = *(const bf16x8*)&Bs[rb * 32 + pbr * 8];
    }
#pragma unroll
    for (int i = 0; i < 2; ++i)
#pragma unroll
      for (int j = 0; j < 4; ++j)
        acc[i][j] = __builtin_amdgcn_mfma_f32_16x16x32_bf16(a[i], b[j], acc[i][j], 0, 0, 0);
    __syncthreads();
  }

  int m0 = row0 + wm * 32, n0 = col0 + wn * 64;
#pragma unroll
  for (int i = 0; i < 2; ++i) {
#pragma unroll
    for (int reg = 0; reg < 4; ++reg) {
      int m = m0 + i * 16 + kg * 4 + reg;
      size_t obase = 0;
      if (MODE == 1) {
        int w = m / 49, nn = m - w * 49;
        int bi = w >> 6, wi = w & 63;
        int hw = wi >> 3, ww = wi & 7;
        int ti = nn / 7, tj = nn - ti * 7;
        int hf = (hw * 7 + ti + 3) % 56, wf = (ww * 7 + tj + 3) % 56;
        obase = ((size_t)bi * 3136 + hf * 56 + wf) * 384;
      }
#pragma unroll
      for (int j = 0; j < 4; ++j) {
        int cN = n0 + j * 16 + lm;
        float v = acc[i][j][reg] + bias[cN];
        if (MODE == 0) {
          ((bf16*)out_)[(size_t)m * N + cN] = f2b(v);
        } else if (MODE == 1) {
          float* O = (float*)out_;
          O[obase + cN] = v + resid[obase + cN];
        } else if (MODE == 2) {
          ((bf16*)out_)[(size_t)m * N + cN] = f2b(gelu_f(v));
        } else {
          float* O = (float*)out_;
          O[(size_t)m * N + cN] = v + resid[(size_t)m * N + cN];
        }
      }
    }
  }
}

// ---------------- MFMA attention: 16B staging loads (was 8B) ----------------
__global__ __launch_bounds__(256) void attn_mfma(const ushort_t* __restrict__ qkv_c,
                                                 const float* __restrict__ table,
                                                 ushort_t* __restrict__ attn_c,
                                                 int w_base) {
  int wl = blockIdx.x >> 2, hg = blockIdx.x & 3;   // 512 windows x 4 head-groups
  int w = w_base + wl;
  int wi = w & 63;
  int hw = wi >> 3, ww = wi & 7;
  __shared__ ushort_t Qs[64 * 40];   // [row m][d], stride 40 (16B-aligned rows)
  __shared__ ushort_t Ks[64 * 40];   // [row n][d]
  __shared__ ushort_t Vt[32 * 72];   // [dcol][key], stride 72
  __shared__ ushort_t Ps[64 * 72];   // [row m][key], stride 72
  __shared__ float bias_s[169 * 12];
  int tid = threadIdx.x;
  int lane = tid & 63, wv = tid >> 6;              // wv = 16-row strip
  int lm = lane & 15, kg = lane >> 4;

  // zero-fill staging pads once (rows/cols >= 49 stay zero across heads)
  for (int i = tid; i < 64 * 40; i += 256) { Qs[i] = 0; Ks[i] = 0; }
  for (int i = tid; i < 32 * 72; i += 256) Vt[i] = 0;
  for (int i = tid; i < 169 * 12; i += 256) bias_s[i] = table[i];
  __syncthreads();

  for (int hh = 0; hh < 3; ++hh) {
    int h = hg * 3 + hh;
    // stage Q,K,V(transposed): 196 x 16B jobs (49 rows x 4 blocks of 8 elems)
    const ushort_t* base = qkv_c + (size_t)wl * 49 * 1152 + h * 32;
    if (tid < 196) {
      int n = tid >> 2, d0 = (tid & 3) * 8;
      const ushort_t* p = base + (size_t)n * 1152 + d0;
      ushort4 q0 = *(const ushort4*)(p);
      ushort4 q1 = *(const ushort4*)(p + 4);
      ushort4 k0 = *(const ushort4*)(p + 384);
      ushort4 k1 = *(const ushort4*)(p + 388);
      ushort4 v0 = *(const ushort4*)(p + 768);
      ushort4 v1 = *(const ushort4*)(p + 772);
      *(ushort4*)&Qs[n * 40 + d0] = q0;
      *(ushort4*)&Qs[n * 40 + d0 + 4] = q1;
      *(ushort4*)&Ks[n * 40 + d0] = k0;
      *(ushort4*)&Ks[n * 40 + d0 + 4] = k1;
      Vt[(d0 + 0) * 72 + n] = v0.x;
      Vt[(d0 + 1) * 72 + n] = v0.y;
      Vt[(d0 + 2) * 72 + n] = v0.z;
      Vt[(d0 + 3) * 72 + n] = v0.w;
      Vt[(d0 + 4) * 72 + n] = v1.x;
      Vt[(d0 + 5) * 72 + n] = v1.y;
      Vt[(d0 + 6) * 72 + n] = v1.z;
      Vt[(d0 + 7) * 72 + n] = v1.w;
    }
    __syncthreads();

    // QK^T: wave's 16-row strip x 64 cols
    bf16x8 qa = *(const bf16x8*)&Qs[(wv * 16 + lm) * 40 + kg * 8];
    f32x4 sacc[4];
#pragma unroll
    for (int jt = 0; jt < 4; ++jt) {
      bf16x8 kb = *(const bf16x8*)&Ks[(jt * 16 + lm) * 40 + kg * 8];
      sacc[jt] = __builtin_amdgcn_mfma_f32_16x16x32_bf16(
          qa, kb, (f32x4){0.f, 0.f, 0.f, 0.f}, 0, 0, 0);
    }

    // softmax rows: row = wv*16 + kg*4 + reg, col = jt*16 + lm
    int i_base = wv * 16 + kg * 4;
#pragma unroll
    for (int reg = 0; reg < 4; ++reg) {
      int i = i_base + reg;
      int ii = (i < 49) ? i : 0;
      int yi = ii / 7, xi = ii - yi * 7;
      int hri = hw * 7 + yi, wri = ww * 7 + xi;
      int ri = (hri < 49 ? 0 : (hri < 53 ? 1 : 2)) * 3 + (wri < 49 ? 0 : (wri < 53 ? 1 : 2));
      float sv[4];
      float mx = -1e30f;
#pragma unroll
      for (int jt = 0; jt < 4; ++jt) {
        int j = jt * 16 + lm;
        int jj = (j < 49) ? j : 0;
        int yj = jj / 7, xj = jj - yj * 7;
        int hrj = hw * 7 + yj, wrj = ww * 7 + xj;
        int rj = (hrj < 49 ? 0 : (hrj < 53 ? 1 : 2)) * 3 + (wrj < 49 ? 0 : (wrj < 53 ? 1 : 2));
        int ridx = (yi - yj + 6) * 13 + (xi - xj + 6);
        float s = sacc[jt][reg] * SCALE_ + bias_s[ridx * 12 + h] + ((ri == rj) ? 0.f : -100.f);
        sv[jt] = (j < 49) ? s : -1e30f;
        mx = fmaxf(mx, sv[jt]);
      }
#pragma unroll
      for (int msk = 1; msk < 16; msk <<= 1) mx = fmaxf(mx, __shfl_xor(mx, msk, 64));
      float sm = 0.f;
#pragma unroll
      for (int jt = 0; jt < 4; ++jt) {
        float e = ((jt * 16 + lm) < 49) ? __expf(sv[jt] - mx) : 0.f;
        sv[jt] = e; sm += e;
      }
#pragma unroll
      for (int msk = 1; msk < 16; msk <<= 1) sm += __shfl_xor(sm, msk, 64);
      float inv = 1.f / sm;   // sm >= 1 (max-subtracted; every row has >=1 valid col)
#pragma unroll
      for (int jt = 0; jt < 4; ++jt) {
        bf16 pb = f2b(sv[jt] * inv);
        Ps[(size_t)i * 72 + jt * 16 + lm] = *(ushort_t*)&pb;
      }
    }
    // PV: O_strip[16][32] = P_strip[16][64] @ V[64][32] (own strip only -> no barrier)
    f32x4 oacc[2] = {(f32x4){0.f, 0.f, 0.f, 0.f}, (f32x4){0.f, 0.f, 0.f, 0.f}};
#pragma unroll
    for (int ks = 0; ks < 2; ++ks) {
      bf16x8 pa = *(const bf16x8*)&Ps[(wv * 16 + lm) * 72 + ks * 32 + kg * 8];
#pragma unroll
      for (int dt = 0; dt < 2; ++dt) {
        bf16x8 vb = *(const bf16x8*)&Vt[(dt * 16 + lm) * 72 + ks * 32 + kg * 8];
        oacc[dt] = __builtin_amdgcn_mfma_f32_16x16x32_bf16(pa, vb, oacc[dt], 0, 0, 0);
      }
    }
#pragma unroll
    for (int reg = 0; reg < 4; ++reg) {
      int r = i_base + reg;
      if (r < 49) {
#pragma unroll
        for (int dt = 0; dt < 2; ++dt) {
          bf16 ob = f2b(oacc[dt][reg]);
          attn_c[((size_t)wl * 49 + r) * 384 + h * 32 + dt * 16 + lm] = *(ushort_t*)&ob;
        }
      }
    }
    __syncthreads();   // protect Qs/Ks/Vt before next head's restage
  }
}

extern "C" void kernel_launch(void* const* d_in, const int* in_sizes, int n_in,
                              void* d_out, int out_size, void* d_ws, size_t ws_size,
                              hipStream_t stream) {
  const float* x      = (const float*)d_in[0];
  const float* ln1_g  = (const float*)d_in[1];
  const float* ln1_b  = (const float*)d_in[2];
  const float* ln2_g  = (const float*)d_in[3];
  const float* ln2_b  = (const float*)d_in[4];
  const float* qkv_w  = (const float*)d_in[5];
  const float* qkv_b  = (const float*)d_in[6];
  const float* proj_w = (const float*)d_in[7];
  const float* proj_b = (const float*)d_in[8];
  const float* mlp_w1 = (const float*)d_in[9];
  const float* mlp_b1 = (const float*)d_in[10];
  const float* mlp_w2 = (const float*)d_in[11];
  const float* mlp_b2 = (const float*)d_in[12];
  const float* rel_tb = (const float*)d_in[13];

  char* ws = (char*)d_ws;
  ushort_t* r0 = (ushort_t*)(ws + 0);                  // 38.5MB: wins / attn_out / ln2o
  ushort_t* r1 = (ushort_t*)(ws + 38535168ull);        // 77MB: qkv chunk / hidden chunk
  ushort_t* wq = (ushort_t*)(ws + 115605504ull);       // bf16 W^T: [1152,384]
  ushort_t* wp = wq + 442368;                          // [384,384]
  ushort_t* w1 = wp + 147456;                          // [1536,384]
  ushort_t* w2 = w1 + 589824;                          // [384,1536]
  float* out = (float*)d_out;

  wt_all<<<6912, 256, 0, stream>>>(qkv_w, proj_w, mlp_w1, mlp_w2, wq, wp, w1, w2);

  ln1_kernel<<<TOKENS / 4, 256, 0, stream>>>(x, ln1_g, ln1_b, (bf16*)r0);

  for (int c = 0; c < 2; ++c) {
    ushort_t* winc = r0 + (size_t)c * CROWS2 * 384;
    mfma_gemm<0><<<(CROWS2 / 128) * 9, 512, 0, stream>>>(
        winc, wq, qkv_b, 1152, 384, nullptr, (void*)r1);
    attn_mfma<<<CW2 * 4, 256, 0, stream>>>(r1, rel_tb, winc, c * CW2);
  }

  mfma_gemm<1><<<(TOKENS / 128) * 3, 512, 0, stream>>>(
      r0, wp, proj_b, 384, 384, x, (void*)out);

  ln2_kernel<<<TOKENS / 4, 256, 0, stream>>>(out, ln2_g, ln2_b, (bf16*)r0);

  for (int c = 0; c < 2; ++c) {
    ushort_t* lc = r0 + (size_t)c * CROWS2 * 384;
    float* oc = out + (size_t)c * CROWS2 * 384;
    mfma_gemm<2><<<(CROWS2 / 128) * 12, 512, 0, stream>>>(
        lc, w1, mlp_b1, 1536, 384, nullptr, (void*)r1);
    mfma_gemm<3><<<(CROWS2 / 128) * 3, 512, 0, stream>>>(
        r1, w2, mlp_b2, 384, 1536, oc, (void*)oc);
  }
}